// Round 12
// baseline (187.254 us; speedup 1.0000x reference)
//
#include <hip/hip_runtime.h>
#include <hip/hip_bf16.h>
#include <hip/hip_fp16.h>
#include <cstdint>

typedef __attribute__((ext_vector_type(8))) short s16x8;
typedef __attribute__((ext_vector_type(8))) _Float16 f16x8;
typedef __attribute__((ext_vector_type(4))) float f32x4;

__device__ __forceinline__ void gload16(const void* g, void* l){
  __builtin_amdgcn_global_load_lds((const __attribute__((address_space(1))) void*)g,
                                   (__attribute__((address_space(3))) void*)l, 16, 0, 0);
}

// transpose + convert: in[K][N] f32 -> outT[N][K] fp16
__global__ void transpose_f16(const float* __restrict__ in, ushort* __restrict__ outT,
                              int K, int N){
  __shared__ float tile[32][33];
  const int kb = blockIdx.y * 32, nb = blockIdx.x * 32;
  const int tx = threadIdx.x & 31, ty = threadIdx.x >> 5;  // ty: 0..7
#pragma unroll
  for (int r = 0; r < 32; r += 8)
    tile[ty + r][tx] = in[(size_t)(kb + ty + r) * N + nb + tx];
  __syncthreads();
#pragma unroll
  for (int r = 0; r < 32; r += 8){
    const float v = tile[tx][ty + r];
    const _Float16 h = (_Float16)v;
    outT[(size_t)(nb + ty + r) * K + kb + tx] = __builtin_bit_cast(ushort, h);
  }
}

// out[32768][10] = b3 broadcast (the gemm2 epilogue atomically accumulates)
__global__ void init_out(float* __restrict__ out, const float* __restrict__ b3, int n4){
  const int i = blockIdx.x * blockDim.x + threadIdx.x;
  if (i >= n4) return;
  f32x4 v;
#pragma unroll
  for (int j = 0; j < 4; ++j) v[j] = b3[(i * 4 + j) % 10];
  ((f32x4*)out)[i] = v;
}

// ---- 128x128-tile fp16 GEMM (R3 structure: 4 waves 2x2, 4 blocks/CU) ---------
// MODE 0: A = x (f32, fused convert via reg-staging), act = blend, store h1 fp16.
// MODE 1: A = h1 (fp16, global_load_lds), act = relu; epilogue fuses GEMM3:
//         h2 tile (LDS fp16) @ W3-slice -> shfl-reduce -> atomicAdd into out.
// LDS: main loop A[128][64] hw 0..8191, B[128][64] hw 8192..16383 (XOR-swizzled
// rows); epilogue reuses [128][128]; MODE1 adds W3 slice [10][128] f32 at hw 16384.
template<int MODE>
__global__ __launch_bounds__(256, 4)
void gemm_fused(const float* __restrict__ Af32, const ushort* __restrict__ A16,
                const ushort* __restrict__ Bw, const float* __restrict__ bias,
                ushort* __restrict__ outH, float* __restrict__ outF,
                const float* __restrict__ W3, int N, int K)
{
  __shared__ ushort lds[MODE == 0 ? 16384 : 18944];
  const int t = threadIdx.x;
  const int lane = t & 63;
  const int wr = (t >> 7) & 1;
  const int wc = (t >> 6) & 1;
  const int ln15 = lane & 15, lnHi = lane >> 4;

  // XCD-aware bijective swizzle (nwg divisible by 8)
  const int gx = gridDim.x;
  const int nwg = gx * gridDim.y;
  const int bid = blockIdx.y * gx + blockIdx.x;
  const int swz = (bid & 7) * (nwg >> 3) + (bid >> 3);
  const int m0 = (swz / gx) * 128;
  const int n0 = (swz % gx) * 128;

  const int srow = t >> 3;        // staging row within 32-row chunk
  const int slot = t & 7;         // 16B-group slot within 128B LDS row

  const ushort* gB = Bw + (size_t)n0 * K;

  if constexpr (MODE == 1){
    float* w3s = (float*)&lds[16384];   // [c][col] = W3[(n0+col)*10 + c]
#pragma unroll
    for (int i2 = 0; i2 < 5; ++i2){
      const int idx = t + i2 * 256;
      const int c = idx >> 7, col = idx & 127;
      w3s[c * 128 + col] = W3[(size_t)(n0 + col) * 10 + c];
    }
  }

  f32x4 acc[4][4] = {};

  for (int kt = 0; kt < K; kt += 64){
    __syncthreads();                 // WAR: prev-tile reads done
    if constexpr (MODE == 0){
      // A: x f32 -> issue loads first (B gloads stay in flight past the cvt wait)
      const float* gAf = Af32 + (size_t)m0 * K;
      f32x4 av[4][2];
#pragma unroll
      for (int c = 0; c < 4; ++c){
        const int row = c * 32 + srow;
        const float* src = gAf + (size_t)row * K + kt + slot * 8;
        av[c][0] = *(const f32x4*)src;
        av[c][1] = *(const f32x4*)(src + 4);
      }
#pragma unroll
      for (int c = 0; c < 4; ++c){
        const int row = c * 32 + srow;
        const int kbyte = (slot << 4) ^ ((row & 7) << 4);
        gload16(gB + (size_t)row * K + kt + (kbyte >> 1),
                &lds[8192 + row * 64 + (slot << 3)]);
      }
#pragma unroll
      for (int c = 0; c < 4; ++c){
        const int row = c * 32 + srow;
        f16x8 hv;
#pragma unroll
        for (int j = 0; j < 4; ++j){
          hv[j]     = (_Float16)av[c][0][j];
          hv[4 + j] = (_Float16)av[c][1][j];
        }
        // direct swizzled ds_write: LDS slot = slot ^ (row&7)
        *(f16x8*)&lds[row * 64 + ((slot ^ (row & 7)) << 3)] = hv;
      }
    } else {
      const ushort* gA = A16 + (size_t)m0 * K;
#pragma unroll
      for (int c = 0; c < 4; ++c){
        const int row = c * 32 + srow;
        const int kbyte = (slot << 4) ^ ((row & 7) << 4);
        gload16(gA + (size_t)row * K + kt + (kbyte >> 1),
                &lds[row * 64 + (slot << 3)]);
        gload16(gB + (size_t)row * K + kt + (kbyte >> 1),
                &lds[8192 + row * 64 + (slot << 3)]);
      }
    }
    __syncthreads();                 // publish (vmcnt + lgkm drain)
#pragma unroll
    for (int s = 0; s < 2; ++s){
      f16x8 af[4], bfv[4];
      const int kb = (s << 6) + (lnHi << 4);
#pragma unroll
      for (int i = 0; i < 4; ++i){
        const int ar = wr * 64 + i * 16 + ln15;
        af[i] = *(const f16x8*)&lds[ar * 64 + ((kb ^ ((ar & 7) << 4)) >> 1)];
        const int br = wc * 64 + i * 16 + ln15;
        bfv[i] = *(const f16x8*)&lds[8192 + br * 64 + ((kb ^ ((br & 7) << 4)) >> 1)];
      }
#pragma unroll
      for (int i = 0; i < 4; ++i)
#pragma unroll
        for (int j = 0; j < 4; ++j)
          acc[i][j] = __builtin_amdgcn_mfma_f32_16x16x32_f16(af[i], bfv[j], acc[i][j], 0, 0, 0);
    }
  }

  // ---- epilogue ----
  __syncthreads();                   // all main-loop LDS reads done
  const int rb_l = wr * 64 + (lnHi << 2);
  const int cb_l = wc * 64 + ln15;
#pragma unroll
  for (int j = 0; j < 4; ++j){
    const int col = cb_l + j * 16;
    const float bv = bias[n0 + col];
#pragma unroll
    for (int i = 0; i < 4; ++i){
#pragma unroll
      for (int r = 0; r < 4; ++r){
        const int row = rb_l + i * 16 + r;
        const float v = acc[i][j][r] + bv;
        float a;
        if (MODE == 0){
          const float th = 1.f - 2.f / (__expf(2.f * v) + 1.f);  // tanh(v)
          a = v > 0.f ? v * 0.9f + th * 0.1f : th * 0.5f;
        } else {
          a = v > 0.f ? v : 0.f;
        }
        const _Float16 h = (_Float16)a;
        lds[row * 128 + (col ^ ((row & 7) << 3))] = __builtin_bit_cast(ushort, h);
      }
    }
  }
  __syncthreads();

  if constexpr (MODE == 0){
    // coalesced fp16 tile store (h1)
#pragma unroll
    for (int k = 0; k < 8; ++k){
      const int chunk = k * 256 + t;          // 128 rows x 16 chunks of 16B
      const int row = chunk >> 4, g = chunk & 15;
      const s16x8 vv = *(const s16x8*)&lds[row * 128 + ((g ^ (row & 7)) << 3)];
      *(s16x8*)&outH[(size_t)(m0 + row) * N + n0 + (g << 3)] = vv;
    }
  } else {
    // fused GEMM3: out[m][c] += sum_col h2[m][col] * W3[n0+col][c]
    const float* w3s = (const float*)&lds[16384];
    const int rg = t >> 3;          // 32 row-groups of 4 rows
    const int cs = t & 7;           // 16-col slice (lane bits 0..2)
    float hv[4][16];
#pragma unroll
    for (int i = 0; i < 4; ++i){
      const int row = rg * 4 + i;
      const f16x8 a0 = *(const f16x8*)&lds[row * 128 + (((cs * 2)     ^ (row & 7)) << 3)];
      const f16x8 a1 = *(const f16x8*)&lds[row * 128 + (((cs * 2 + 1) ^ (row & 7)) << 3)];
#pragma unroll
      for (int k = 0; k < 8; ++k){
        hv[i][k]     = (float)a0[k];
        hv[i][8 + k] = (float)a1[k];
      }
    }
    float oacc[4][10];
#pragma unroll
    for (int c = 0; c < 10; ++c){
      const f32x4 w0 = *(const f32x4*)&w3s[c * 128 + cs * 16];
      const f32x4 w1 = *(const f32x4*)&w3s[c * 128 + cs * 16 + 4];
      const f32x4 w2 = *(const f32x4*)&w3s[c * 128 + cs * 16 + 8];
      const f32x4 w3v= *(const f32x4*)&w3s[c * 128 + cs * 16 + 12];
#pragma unroll
      for (int i = 0; i < 4; ++i){
        float s = 0.f;
#pragma unroll
        for (int k = 0; k < 4; ++k){
          s += hv[i][k]      * w0[k];
          s += hv[i][4 + k]  * w1[k];
          s += hv[i][8 + k]  * w2[k];
          s += hv[i][12 + k] * w3v[k];
        }
        oacc[i][c] = s;
      }
    }
#pragma unroll
    for (int off = 1; off <= 4; off <<= 1)
#pragma unroll
      for (int i = 0; i < 4; ++i)
#pragma unroll
        for (int c = 0; c < 10; ++c)
          oacc[i][c] += __shfl_xor(oacc[i][c], off);
    if (cs == 0){
#pragma unroll
      for (int i = 0; i < 4; ++i)
#pragma unroll
        for (int c = 0; c < 10; ++c)
          atomicAdd(&outF[(size_t)(m0 + rg * 4 + i) * 10 + c], oacc[i][c]);
    }
  }
}

extern "C" void kernel_launch(void* const* d_in, const int* in_sizes, int n_in,
                              void* d_out, int out_size, void* d_ws, size_t ws_size,
                              hipStream_t stream){
  const float* x  = (const float*)d_in[0];
  const float* W1 = (const float*)d_in[1];
  const float* b1 = (const float*)d_in[2];
  const float* W2 = (const float*)d_in[3];
  const float* b2 = (const float*)d_in[4];
  const float* W3 = (const float*)d_in[5];
  const float* b3 = (const float*)d_in[6];
  float* out = (float*)d_out;

  const int B = 32768, Din = 512, H = 1024, Hh = 512;
  char* ws = (char*)d_ws;
  const size_t MB = (size_t)1 << 20;
  // ws layout (~66 MB):
  ushort* h1  = (ushort*)(ws);            // 64 MB  (32768 x 1024 fp16)
  ushort* W1T = (ushort*)(ws + 64 * MB);  // 1 MB   (1024 x 512 fp16)
  ushort* W2T = (ushort*)(ws + 65 * MB);  // 1 MB   (512 x 1024 fp16)

  transpose_f16<<<dim3(H / 32, Din / 32), 256, 0, stream>>>(W1, W1T, Din, H);
  transpose_f16<<<dim3(Hh / 32, H / 32), 256, 0, stream>>>(W2, W2T, H, Hh);
  init_out<<<(B * 10 / 4 + 255) / 256, 256, 0, stream>>>(out, b3, B * 10 / 4);

  gemm_fused<0><<<dim3(H / 128, B / 128), 256, 0, stream>>>(
      x, nullptr, W1T, b1, h1, nullptr, nullptr, H, Din);
  gemm_fused<1><<<dim3(Hh / 128, B / 128), 256, 0, stream>>>(
      nullptr, h1, W2T, b2, nullptr, out, W3, Hh, H);
}